// Round 6
// baseline (766.906 us; speedup 1.0000x reference)
//
#include <hip/hip_runtime.h>
#include <hip/hip_bf16.h>

typedef __bf16 bf16;
typedef __attribute__((ext_vector_type(4)))  float  f32x4;
typedef __attribute__((ext_vector_type(16))) float  f32x16;
typedef __attribute__((ext_vector_type(8)))  __bf16 bf16x8;
typedef __attribute__((ext_vector_type(4)))  __bf16 bf16x4;

#define NB    4
#define NSEQ  2048
#define DIM   1024
#define NH    8
#define DHEAD 64
#define INNER 512

// ---------------- weight prep: transpose + fp32->bf16 ------------------------
// Wq gets SCALE (64^-0.5) AND log2(e) folded in so attention softmax runs in
// exp2 domain with no per-element multiply.
__global__ __launch_bounds__(256) void prep_w(const float* __restrict__ Wq,
                                              const float* __restrict__ Wkv,
                                              const float* __restrict__ Wo,
                                              bf16* __restrict__ Wqkv_t,
                                              bf16* __restrict__ Wo_t) {
    int gid = blockIdx.x * 256 + threadIdx.x;
    const int N1 = 640 * 1024;            // Wqkv_t: 640 rows (n) x 1024 (k)
    if (gid < N1) {
        int n = gid >> 10, k = gid & 1023;
        float v;
        if (n < 512) v = Wq[k * 512 + n] * (0.125f * 1.44269504088896f);
        else         v = Wkv[k * 128 + (n - 512)];
        Wqkv_t[gid] = (bf16)v;
    } else {
        int g = gid - N1;                 // Wo_t: 1024 rows (n) x 512 (k)
        int n = g >> 9, k = g & 511;
        Wo_t[g] = (bf16)Wo[k * 1024 + n];
    }
}

// ---------------- layernorm fp32 -> bf16 ------------------------------------
__global__ __launch_bounds__(256) void ln_bf16(const float* __restrict__ x,
                                               const float* __restrict__ w,
                                               const float* __restrict__ b,
                                               bf16* __restrict__ out) {
    int row = blockIdx.x, tid = threadIdx.x;
    const float* xr = x + (size_t)row * DIM;
    f32x4 v = *reinterpret_cast<const f32x4*>(xr + tid * 4);
    float s1 = v[0] + v[1] + v[2] + v[3];
    float s2 = v[0]*v[0] + v[1]*v[1] + v[2]*v[2] + v[3]*v[3];
    #pragma unroll
    for (int off = 32; off; off >>= 1) { s1 += __shfl_xor(s1, off); s2 += __shfl_xor(s2, off); }
    __shared__ float red[8];
    int wid = tid >> 6, lane = tid & 63;
    if (!lane) { red[wid] = s1; red[4 + wid] = s2; }
    __syncthreads();
    s1 = red[0] + red[1] + red[2] + red[3];
    s2 = red[4] + red[5] + red[6] + red[7];
    float mu = s1 * (1.0f / DIM);
    float var = s2 * (1.0f / DIM) - mu * mu;
    float rs = rsqrtf(var + 1e-5f);
    f32x4 wv = *reinterpret_cast<const f32x4*>(w + tid * 4);
    f32x4 bv = *reinterpret_cast<const f32x4*>(b + tid * 4);
    bf16x4 o;
    #pragma unroll
    for (int i = 0; i < 4; i++) o[i] = (bf16)((v[i] - mu) * rs * wv[i] + bv[i]);
    *reinterpret_cast<bf16x4*>(out + (size_t)row * DIM + tid * 4) = o;
}

// ---------------- layernorm fp32 -> fp32 (in-place safe: row-local) ---------
__global__ __launch_bounds__(256) void ln_f32(float* __restrict__ io,
                                              const float* __restrict__ w,
                                              const float* __restrict__ b) {
    int row = blockIdx.x, tid = threadIdx.x;
    float* xr = io + (size_t)row * DIM;
    f32x4 v = *reinterpret_cast<const f32x4*>(xr + tid * 4);
    float s1 = v[0] + v[1] + v[2] + v[3];
    float s2 = v[0]*v[0] + v[1]*v[1] + v[2]*v[2] + v[3]*v[3];
    #pragma unroll
    for (int off = 32; off; off >>= 1) { s1 += __shfl_xor(s1, off); s2 += __shfl_xor(s2, off); }
    __shared__ float red[8];
    int wid = tid >> 6, lane = tid & 63;
    if (!lane) { red[wid] = s1; red[4 + wid] = s2; }
    __syncthreads();
    s1 = red[0] + red[1] + red[2] + red[3];
    s2 = red[4] + red[5] + red[6] + red[7];
    float mu = s1 * (1.0f / DIM);
    float var = s2 * (1.0f / DIM) - mu * mu;
    float rs = rsqrtf(var + 1e-5f);
    f32x4 wv = *reinterpret_cast<const f32x4*>(w + tid * 4);
    f32x4 bv = *reinterpret_cast<const f32x4*>(b + tid * 4);
    f32x4 o;
    #pragma unroll
    for (int i = 0; i < 4; i++) o[i] = (v[i] - mu) * rs * wv[i] + bv[i];
    *reinterpret_cast<f32x4*>(xr + tid * 4) = o;
}

// ---------------- GEMM  C = A(M x K) * Bt(N x K)^T,  bf16 MFMA 32x32x16 -----
template<int EPI>
__global__ __launch_bounds__(256)
void gemm_bt(const bf16* __restrict__ A, const bf16* __restrict__ Bt,
             int K, int ntiles,
             bf16* __restrict__ qo, bf16* __restrict__ ko, bf16* __restrict__ vo,
             float* __restrict__ fo) {
    __shared__ __align__(16) bf16 As[128 * 64];
    __shared__ __align__(16) bf16 Bs[64 * 64];
    int bid = blockIdx.x;
    int mt = bid / ntiles, nt = bid % ntiles;
    int m0 = mt * 128, n0 = nt * 64;
    int tid = threadIdx.x, lane = tid & 63, wid = tid >> 6;
    int wr = wid >> 1, wc = wid & 1;

    f32x16 acc[2];
    #pragma unroll
    for (int rt = 0; rt < 2; rt++)
        #pragma unroll
        for (int i = 0; i < 16; i++) acc[rt][i] = 0.f;

    char* AsB = reinterpret_cast<char*>(As);
    char* BsB = reinterpret_cast<char*>(Bs);

    for (int k0 = 0; k0 < K; k0 += 64) {
        #pragma unroll
        for (int i = 0; i < 4; i++) {           // A tile: 128 rows x 8 chunks(16B)
            int c = tid + 256 * i;
            int row = c >> 3, c16 = c & 7;
            f32x4 d = *reinterpret_cast<const f32x4*>(A + (size_t)(m0 + row) * K + k0 + c16 * 8);
            *reinterpret_cast<f32x4*>(AsB + row * 128 + ((c16 ^ (row & 7)) * 16)) = d;
        }
        #pragma unroll
        for (int i = 0; i < 2; i++) {           // B tile: 64 rows x 8 chunks
            int c = tid + 256 * i;
            int row = c >> 3, c16 = c & 7;
            f32x4 d = *reinterpret_cast<const f32x4*>(Bt + (size_t)(n0 + row) * K + k0 + c16 * 8);
            *reinterpret_cast<f32x4*>(BsB + row * 128 + ((c16 ^ (row & 7)) * 16)) = d;
        }
        __syncthreads();
        #pragma unroll
        for (int kc = 0; kc < 4; kc++) {
            int c16 = kc * 2 + (lane >> 5);
            int bn = wc * 32 + (lane & 31);
            bf16x8 bfr = *reinterpret_cast<bf16x8*>(BsB + bn * 128 + ((c16 ^ (bn & 7)) * 16));
            #pragma unroll
            for (int rt = 0; rt < 2; rt++) {
                int ar = wr * 64 + rt * 32 + (lane & 31);
                bf16x8 afr = *reinterpret_cast<bf16x8*>(AsB + ar * 128 + ((c16 ^ (ar & 7)) * 16));
                acc[rt] = __builtin_amdgcn_mfma_f32_32x32x16_bf16(afr, bfr, acc[rt], 0, 0, 0);
            }
        }
        __syncthreads();
    }

    int col = wc * 32 + (lane & 31);
    int gn = n0 + col;
    #pragma unroll
    for (int rt = 0; rt < 2; rt++) {
        int rbase = m0 + wr * 64 + rt * 32 + 4 * (lane >> 5);
        if (EPI == 0) {
            if (n0 < 512) {                     // q -> (b, h, n, d), scale pre-folded
                int h = gn >> 6, d = gn & 63;
                #pragma unroll
                for (int r = 0; r < 16; r++) {
                    int row = rbase + (r & 3) + 8 * (r >> 2);
                    int bb = row >> 11, seq = row & 2047;
                    qo[(((size_t)(bb * NH + h) * NSEQ + seq) << 6) + d] = (bf16)acc[rt][r];
                }
            } else if (n0 < 576) {              // k -> (b, n, d)
                int d = gn - 512;
                #pragma unroll
                for (int r = 0; r < 16; r++) {
                    int row = rbase + (r & 3) + 8 * (r >> 2);
                    int bb = row >> 11, seq = row & 2047;
                    ko[(((size_t)bb * NSEQ + seq) << 6) + d] = (bf16)acc[rt][r];
                }
            } else {                            // v -> transposed (b, d, n), packed x4
                int d = gn - 576;
                #pragma unroll
                for (int rq = 0; rq < 4; rq++) {
                    int row = rbase + 8 * rq;
                    int bb = row >> 11, seq = row & 2047;
                    bf16x4 pk;
                    #pragma unroll
                    for (int j = 0; j < 4; j++) pk[j] = (bf16)acc[rt][rq * 4 + j];
                    *reinterpret_cast<bf16x4*>(vo + (size_t)(bb * 64 + d) * NSEQ + seq) = pk;
                }
            }
        } else {                                // fp32 linear output, N=1024
            #pragma unroll
            for (int r = 0; r < 16; r++) {
                int row = rbase + (r & 3) + 8 * (r >> 2);
                fo[(size_t)row * 1024 + gn] = acc[rt][r];
            }
        }
    }
}

static __device__ __forceinline__ unsigned packbf(float a, float b) {
    union { unsigned u; bf16 h[2]; } t;
    t.h[0] = (bf16)a; t.h[1] = (bf16)b;
    return t.u;
}

// ---------------- flash attention: in-block split-KV x4 ----------------------
// One block per (bh, qtile-of-32). Wave w handles KV chunk [w*512,(w+1)*512),
// identical swapped-QK / in-register-softmax loop as round 5 (verified).
// Block-level flash merge in LDS: m* = max_w m_w; each wave scales its O,l by
// exp2(m_w - m*); O tree-summed (waves 2,3 -> 0,1; wave 1 -> 0); wave 0 writes.
// VGPR must stay <=64 for 8 waves/SIMD -> __launch_bounds__(256, 8).
__global__ __launch_bounds__(256, 8)
void attn(const bf16* __restrict__ q, const bf16* __restrict__ k,
          const bf16* __restrict__ vt, bf16* __restrict__ o) {
    __shared__ float mlds[4][32][2];                     // [wave][q][m,l]
    __shared__ __align__(16) float olds[2][32][64];      // [region][reg][lane] 16 KB
    int tid = threadIdx.x, lane = tid & 63, wid = tid >> 6;
    int ln = lane & 31, hi = lane >> 5, hi8 = hi * 8;
    int bh = blockIdx.x >> 6, qt = blockIdx.x & 63;
    int b = bh >> 3, h = bh & 7;
    int q0 = qt * 32;

    // Q fragments (B-operand): lane holds Q[q0+ln][c*16 + hi8 + 0..7]
    const bf16* qb = q + (((size_t)bh * NSEQ + q0 + ln) << 6) + hi8;
    bf16x8 qf0 = *reinterpret_cast<const bf16x8*>(qb);
    bf16x8 qf1 = *reinterpret_cast<const bf16x8*>(qb + 16);
    bf16x8 qf2 = *reinterpret_cast<const bf16x8*>(qb + 32);
    bf16x8 qf3 = *reinterpret_cast<const bf16x8*>(qb + 48);

    int kv_lo = wid << 9;                                // wave's 512-KV chunk
    const bf16* kr = k + (((size_t)b * NSEQ + kv_lo + ln) << 6) + hi8;
    const bf16* vr = vt + ((size_t)b * 64 + ln) * NSEQ + kv_lo + hi8;

    float m = -INFINITY, l = 0.f;
    f32x16 o0, o1;
    #pragma unroll
    for (int i = 0; i < 16; i++) { o0[i] = 0.f; o1[i] = 0.f; }

    for (int it = 0; it < 16; ++it) {
        // --- K fragments (A-operand)
        bf16x8 kf0 = *reinterpret_cast<const bf16x8*>(kr);
        bf16x8 kf1 = *reinterpret_cast<const bf16x8*>(kr + 16);
        bf16x8 kf2 = *reinterpret_cast<const bf16x8*>(kr + 32);
        bf16x8 kf3 = *reinterpret_cast<const bf16x8*>(kr + 48);
        kr += 32 * 64;

        // --- S^T (32 kv x 32 q), log2-scaled logits
        f32x16 s;
        #pragma unroll
        for (int i = 0; i < 16; i++) s[i] = 0.f;
        s = __builtin_amdgcn_mfma_f32_32x32x16_bf16(kf0, qf0, s, 0, 0, 0);
        s = __builtin_amdgcn_mfma_f32_32x32x16_bf16(kf1, qf1, s, 0, 0, 0);
        s = __builtin_amdgcn_mfma_f32_32x32x16_bf16(kf2, qf2, s, 0, 0, 0);
        s = __builtin_amdgcn_mfma_f32_32x32x16_bf16(kf3, qf3, s, 0, 0, 0);

        // --- V^T fragments for PV (issue loads early; overlap with softmax)
        bf16x8 v00 = *reinterpret_cast<const bf16x8*>(vr);
        bf16x8 v01 = *reinterpret_cast<const bf16x8*>(vr + 16);
        bf16x8 v10 = *reinterpret_cast<const bf16x8*>(vr + 32 * NSEQ);
        bf16x8 v11 = *reinterpret_cast<const bf16x8*>(vr + 32 * NSEQ + 16);
        vr += 32;

        // --- tile max over the 32 kv entries of this q (tree + cross-half shfl)
        float t8[8];
        #pragma unroll
        for (int i = 0; i < 8; i++) t8[i] = fmaxf(s[2 * i], s[2 * i + 1]);
        float t4a = fmaxf(t8[0], t8[1]), t4b = fmaxf(t8[2], t8[3]);
        float t4c = fmaxf(t8[4], t8[5]), t4d = fmaxf(t8[6], t8[7]);
        float tmax = fmaxf(fmaxf(t4a, t4b), fmaxf(t4c, t4d));
        tmax = fmaxf(tmax, __shfl_xor(tmax, 32));

        // --- defer-max rescale (T13, THR=8 in log2 domain)
        if (__any(tmax > m + 8.0f)) {
            float mn = fmaxf(m, tmax);
            float sc = __builtin_amdgcn_exp2f(m - mn);
            m = mn; l *= sc;
            #pragma unroll
            for (int i = 0; i < 16; i++) { o0[i] *= sc; o1[i] *= sc; }
        }

        // --- P = exp2(S - m), row-sum
        float p[16];
        #pragma unroll
        for (int i = 0; i < 16; i++) p[i] = __builtin_amdgcn_exp2f(s[i] - m);
        float u8[8];
        #pragma unroll
        for (int i = 0; i < 8; i++) u8[i] = p[2 * i] + p[2 * i + 1];
        float u4a = u8[0] + u8[1], u4b = u8[2] + u8[3];
        float u4c = u8[4] + u8[5], u4d = u8[6] + u8[7];
        float su = (u4a + u4b) + (u4c + u4d);
        su += __shfl_xor(su, 32);
        l += su;

        // --- P -> bf16 PV B-fragments (pack + shfl_xor(32) + select)
        unsigned A0 = packbf(p[0],  p[1]),  A1 = packbf(p[2],  p[3]);
        unsigned B0 = packbf(p[4],  p[5]),  B1 = packbf(p[6],  p[7]);
        unsigned C0 = packbf(p[8],  p[9]),  C1 = packbf(p[10], p[11]);
        unsigned D0 = packbf(p[12], p[13]), D1 = packbf(p[14], p[15]);
        unsigned A0x = __shfl_xor(A0, 32), A1x = __shfl_xor(A1, 32);
        unsigned B0x = __shfl_xor(B0, 32), B1x = __shfl_xor(B1, 32);
        unsigned C0x = __shfl_xor(C0, 32), C1x = __shfl_xor(C1, 32);
        unsigned D0x = __shfl_xor(D0, 32), D1x = __shfl_xor(D1, 32);
        union U { unsigned u[4]; bf16x8 v; } pf0, pf1;
        pf0.u[0] = hi ? B0x : A0;  pf0.u[1] = hi ? B1x : A1;
        pf0.u[2] = hi ? B0  : A0x; pf0.u[3] = hi ? B1  : A1x;
        pf1.u[0] = hi ? D0x : C0;  pf1.u[1] = hi ? D1x : C1;
        pf1.u[2] = hi ? D0  : C0x; pf1.u[3] = hi ? D1  : C1x;

        // --- O^T += V^T P   (two d-halves x two kv chunks)
        o0 = __builtin_amdgcn_mfma_f32_32x32x16_bf16(v00, pf0.v, o0, 0, 0, 0);
        o0 = __builtin_amdgcn_mfma_f32_32x32x16_bf16(v01, pf1.v, o0, 0, 0, 0);
        o1 = __builtin_amdgcn_mfma_f32_32x32x16_bf16(v10, pf0.v, o1, 0, 0, 0);
        o1 = __builtin_amdgcn_mfma_f32_32x32x16_bf16(v11, pf1.v, o1, 0, 0, 0);
    }

    // ---- block-level flash merge across the 4 KV-split waves ----
    if (!hi) { mlds[wid][ln][0] = m; mlds[wid][ln][1] = l; }
    __syncthreads();
    float m0 = mlds[0][ln][0], m1 = mlds[1][ln][0];
    float m2 = mlds[2][ln][0], m3 = mlds[3][ln][0];
    float mstar = fmaxf(fmaxf(m0, m1), fmaxf(m2, m3));
    float lstar = mlds[0][ln][1] * __builtin_amdgcn_exp2f(m0 - mstar)
                + mlds[1][ln][1] * __builtin_amdgcn_exp2f(m1 - mstar)
                + mlds[2][ln][1] * __builtin_amdgcn_exp2f(m2 - mstar)
                + mlds[3][ln][1] * __builtin_amdgcn_exp2f(m3 - mstar);
    float msc = __builtin_amdgcn_exp2f(m - mstar);
    #pragma unroll
    for (int i = 0; i < 16; i++) { o0[i] *= msc; o1[i] *= msc; }

    if (wid >= 2) {
        #pragma unroll
        for (int i = 0; i < 16; i++) {
            olds[wid - 2][i][lane]      = o0[i];
            olds[wid - 2][16 + i][lane] = o1[i];
        }
    }
    __syncthreads();
    if (wid < 2) {
        #pragma unroll
        for (int i = 0; i < 16; i++) {
            o0[i] += olds[wid][i][lane];
            o1[i] += olds[wid][16 + i][lane];
        }
    }
    __syncthreads();
    if (wid == 1) {
        #pragma unroll
        for (int i = 0; i < 16; i++) {
            olds[0][i][lane]      = o0[i];
            olds[0][16 + i][lane] = o1[i];
        }
    }
    __syncthreads();
    if (wid == 0) {
        #pragma unroll
        for (int i = 0; i < 16; i++) {
            o0[i] += olds[0][i][lane];
            o1[i] += olds[0][16 + i][lane];
        }
        float rl = 1.0f / lstar;
        bf16* ob = o + ((size_t)(b * NSEQ + q0 + ln)) * INNER + h * 64 + hi * 4;
        #pragma unroll
        for (int dh = 0; dh < 2; dh++) {
            const f32x16& oo = dh ? o1 : o0;
            #pragma unroll
            for (int g = 0; g < 4; g++) {
                bf16x4 pk;
                #pragma unroll
                for (int j = 0; j < 4; j++) pk[j] = (bf16)(oo[g * 4 + j] * rl);
                *reinterpret_cast<bf16x4*>(ob + dh * 32 + g * 8) = pk;
            }
        }
    }
}

// ---------------- launch -----------------------------------------------------
extern "C" void kernel_launch(void* const* d_in, const int* in_sizes, int n_in,
                              void* d_out, int out_size, void* d_ws, size_t ws_size,
                              hipStream_t stream) {
    const float* x   = (const float*)d_in[0];
    const float* Wq  = (const float*)d_in[1];
    const float* Wkv = (const float*)d_in[2];
    const float* Wo  = (const float*)d_in[3];
    const float* nw  = (const float*)d_in[4];
    const float* nb  = (const float*)d_in[5];
    const float* onw = (const float*)d_in[6];
    const float* onb = (const float*)d_in[7];
    float* out = (float*)d_out;
    char* ws = (char*)d_ws;

    bf16* xn   = (bf16*)(ws);                   // 16 MB  (8192x1024)
    bf16* qs   = (bf16*)(ws + (16u << 20));     //  8 MB  (4,8,2048,64)
    bf16* ks   = (bf16*)(ws + (24u << 20));     //  1 MB  (4,2048,64)
    bf16* vts  = (bf16*)(ws + (25u << 20));     //  1 MB  (4,64,2048)
    bf16* ao   = (bf16*)(ws + (26u << 20));     //  8 MB  (8192x512)
    bf16* wqkv = (bf16*)(ws + (34u << 20));     //  1.25 MB (640x1024)
    bf16* wo   = (bf16*)(ws + (36u << 20));     //  1 MB  (1024x512)

    prep_w<<<4608, 256, 0, stream>>>(Wq, Wkv, Wo, wqkv, wo);
    ln_bf16<<<8192, 256, 0, stream>>>(x, nw, nb, xn);
    gemm_bt<0><<<64 * 10, 256, 0, stream>>>(xn, wqkv, 1024, 10, qs, ks, vts, nullptr);
    attn<<<2048, 256, 0, stream>>>(qs, ks, vts, ao);
    gemm_bt<1><<<64 * 16, 256, 0, stream>>>(ao, wo, 512, 16, nullptr, nullptr, nullptr, out);
    ln_f32<<<8192, 256, 0, stream>>>(out, onw, onb);
}

// Round 7
// 276.714 us; speedup vs baseline: 2.7715x; 2.7715x over previous
//
#include <hip/hip_runtime.h>
#include <hip/hip_bf16.h>

typedef __bf16 bf16;
typedef __attribute__((ext_vector_type(4)))  float  f32x4;
typedef __attribute__((ext_vector_type(16))) float  f32x16;
typedef __attribute__((ext_vector_type(8)))  __bf16 bf16x8;
typedef __attribute__((ext_vector_type(4)))  __bf16 bf16x4;

#define NB    4
#define NSEQ  2048
#define DIM   1024
#define NH    8
#define DHEAD 64
#define INNER 512

// ---------------- weight prep: transpose + fp32->bf16 ------------------------
// Wq gets SCALE (64^-0.5) AND log2(e) folded in so attention softmax runs in
// exp2 domain with no per-element multiply.
__global__ __launch_bounds__(256) void prep_w(const float* __restrict__ Wq,
                                              const float* __restrict__ Wkv,
                                              const float* __restrict__ Wo,
                                              bf16* __restrict__ Wqkv_t,
                                              bf16* __restrict__ Wo_t) {
    int gid = blockIdx.x * 256 + threadIdx.x;
    const int N1 = 640 * 1024;            // Wqkv_t: 640 rows (n) x 1024 (k)
    if (gid < N1) {
        int n = gid >> 10, k = gid & 1023;
        float v;
        if (n < 512) v = Wq[k * 512 + n] * (0.125f * 1.44269504088896f);
        else         v = Wkv[k * 128 + (n - 512)];
        Wqkv_t[gid] = (bf16)v;
    } else {
        int g = gid - N1;                 // Wo_t: 1024 rows (n) x 512 (k)
        int n = g >> 9, k = g & 511;
        Wo_t[g] = (bf16)Wo[k * 1024 + n];
    }
}

// ---------------- layernorm fp32 -> bf16 ------------------------------------
__global__ __launch_bounds__(256) void ln_bf16(const float* __restrict__ x,
                                               const float* __restrict__ w,
                                               const float* __restrict__ b,
                                               bf16* __restrict__ out) {
    int row = blockIdx.x, tid = threadIdx.x;
    const float* xr = x + (size_t)row * DIM;
    f32x4 v = *reinterpret_cast<const f32x4*>(xr + tid * 4);
    float s1 = v[0] + v[1] + v[2] + v[3];
    float s2 = v[0]*v[0] + v[1]*v[1] + v[2]*v[2] + v[3]*v[3];
    #pragma unroll
    for (int off = 32; off; off >>= 1) { s1 += __shfl_xor(s1, off); s2 += __shfl_xor(s2, off); }
    __shared__ float red[8];
    int wid = tid >> 6, lane = tid & 63;
    if (!lane) { red[wid] = s1; red[4 + wid] = s2; }
    __syncthreads();
    s1 = red[0] + red[1] + red[2] + red[3];
    s2 = red[4] + red[5] + red[6] + red[7];
    float mu = s1 * (1.0f / DIM);
    float var = s2 * (1.0f / DIM) - mu * mu;
    float rs = rsqrtf(var + 1e-5f);
    f32x4 wv = *reinterpret_cast<const f32x4*>(w + tid * 4);
    f32x4 bv = *reinterpret_cast<const f32x4*>(b + tid * 4);
    bf16x4 o;
    #pragma unroll
    for (int i = 0; i < 4; i++) o[i] = (bf16)((v[i] - mu) * rs * wv[i] + bv[i]);
    *reinterpret_cast<bf16x4*>(out + (size_t)row * DIM + tid * 4) = o;
}

// ---------------- layernorm fp32 -> fp32 (in-place safe: row-local) ---------
__global__ __launch_bounds__(256) void ln_f32(float* __restrict__ io,
                                              const float* __restrict__ w,
                                              const float* __restrict__ b) {
    int row = blockIdx.x, tid = threadIdx.x;
    float* xr = io + (size_t)row * DIM;
    f32x4 v = *reinterpret_cast<const f32x4*>(xr + tid * 4);
    float s1 = v[0] + v[1] + v[2] + v[3];
    float s2 = v[0]*v[0] + v[1]*v[1] + v[2]*v[2] + v[3]*v[3];
    #pragma unroll
    for (int off = 32; off; off >>= 1) { s1 += __shfl_xor(s1, off); s2 += __shfl_xor(s2, off); }
    __shared__ float red[8];
    int wid = tid >> 6, lane = tid & 63;
    if (!lane) { red[wid] = s1; red[4 + wid] = s2; }
    __syncthreads();
    s1 = red[0] + red[1] + red[2] + red[3];
    s2 = red[4] + red[5] + red[6] + red[7];
    float mu = s1 * (1.0f / DIM);
    float var = s2 * (1.0f / DIM) - mu * mu;
    float rs = rsqrtf(var + 1e-5f);
    f32x4 wv = *reinterpret_cast<const f32x4*>(w + tid * 4);
    f32x4 bv = *reinterpret_cast<const f32x4*>(b + tid * 4);
    f32x4 o;
    #pragma unroll
    for (int i = 0; i < 4; i++) o[i] = (v[i] - mu) * rs * wv[i] + bv[i];
    *reinterpret_cast<f32x4*>(xr + tid * 4) = o;
}

// ---------------- GEMM  C = A(M x K) * Bt(N x K)^T,  bf16 MFMA 32x32x16 -----
template<int EPI>
__global__ __launch_bounds__(256)
void gemm_bt(const bf16* __restrict__ A, const bf16* __restrict__ Bt,
             int K, int ntiles,
             bf16* __restrict__ qo, bf16* __restrict__ ko, bf16* __restrict__ vo,
             float* __restrict__ fo) {
    __shared__ __align__(16) bf16 As[128 * 64];
    __shared__ __align__(16) bf16 Bs[64 * 64];
    int bid = blockIdx.x;
    int mt = bid / ntiles, nt = bid % ntiles;
    int m0 = mt * 128, n0 = nt * 64;
    int tid = threadIdx.x, lane = tid & 63, wid = tid >> 6;
    int wr = wid >> 1, wc = wid & 1;

    f32x16 acc[2];
    #pragma unroll
    for (int rt = 0; rt < 2; rt++)
        #pragma unroll
        for (int i = 0; i < 16; i++) acc[rt][i] = 0.f;

    char* AsB = reinterpret_cast<char*>(As);
    char* BsB = reinterpret_cast<char*>(Bs);

    for (int k0 = 0; k0 < K; k0 += 64) {
        #pragma unroll
        for (int i = 0; i < 4; i++) {           // A tile: 128 rows x 8 chunks(16B)
            int c = tid + 256 * i;
            int row = c >> 3, c16 = c & 7;
            f32x4 d = *reinterpret_cast<const f32x4*>(A + (size_t)(m0 + row) * K + k0 + c16 * 8);
            *reinterpret_cast<f32x4*>(AsB + row * 128 + ((c16 ^ (row & 7)) * 16)) = d;
        }
        #pragma unroll
        for (int i = 0; i < 2; i++) {           // B tile: 64 rows x 8 chunks
            int c = tid + 256 * i;
            int row = c >> 3, c16 = c & 7;
            f32x4 d = *reinterpret_cast<const f32x4*>(Bt + (size_t)(n0 + row) * K + k0 + c16 * 8);
            *reinterpret_cast<f32x4*>(BsB + row * 128 + ((c16 ^ (row & 7)) * 16)) = d;
        }
        __syncthreads();
        #pragma unroll
        for (int kc = 0; kc < 4; kc++) {
            int c16 = kc * 2 + (lane >> 5);
            int bn = wc * 32 + (lane & 31);
            bf16x8 bfr = *reinterpret_cast<bf16x8*>(BsB + bn * 128 + ((c16 ^ (bn & 7)) * 16));
            #pragma unroll
            for (int rt = 0; rt < 2; rt++) {
                int ar = wr * 64 + rt * 32 + (lane & 31);
                bf16x8 afr = *reinterpret_cast<bf16x8*>(AsB + ar * 128 + ((c16 ^ (ar & 7)) * 16));
                acc[rt] = __builtin_amdgcn_mfma_f32_32x32x16_bf16(afr, bfr, acc[rt], 0, 0, 0);
            }
        }
        __syncthreads();
    }

    int col = wc * 32 + (lane & 31);
    int gn = n0 + col;
    #pragma unroll
    for (int rt = 0; rt < 2; rt++) {
        int rbase = m0 + wr * 64 + rt * 32 + 4 * (lane >> 5);
        if (EPI == 0) {
            if (n0 < 512) {                     // q -> (b, h, n, d), scale pre-folded
                int h = gn >> 6, d = gn & 63;
                #pragma unroll
                for (int r = 0; r < 16; r++) {
                    int row = rbase + (r & 3) + 8 * (r >> 2);
                    int bb = row >> 11, seq = row & 2047;
                    qo[(((size_t)(bb * NH + h) * NSEQ + seq) << 6) + d] = (bf16)acc[rt][r];
                }
            } else if (n0 < 576) {              // k -> (b, n, d)
                int d = gn - 512;
                #pragma unroll
                for (int r = 0; r < 16; r++) {
                    int row = rbase + (r & 3) + 8 * (r >> 2);
                    int bb = row >> 11, seq = row & 2047;
                    ko[(((size_t)bb * NSEQ + seq) << 6) + d] = (bf16)acc[rt][r];
                }
            } else {                            // v -> transposed (b, d, n), packed x4
                int d = gn - 576;
                #pragma unroll
                for (int rq = 0; rq < 4; rq++) {
                    int row = rbase + 8 * rq;
                    int bb = row >> 11, seq = row & 2047;
                    bf16x4 pk;
                    #pragma unroll
                    for (int j = 0; j < 4; j++) pk[j] = (bf16)acc[rt][rq * 4 + j];
                    *reinterpret_cast<bf16x4*>(vo + (size_t)(bb * 64 + d) * NSEQ + seq) = pk;
                }
            }
        } else {                                // fp32 linear output, N=1024
            #pragma unroll
            for (int r = 0; r < 16; r++) {
                int row = rbase + (r & 3) + 8 * (r >> 2);
                fo[(size_t)row * 1024 + gn] = acc[rt][r];
            }
        }
    }
}

static __device__ __forceinline__ unsigned packbf(float a, float b) {
    union { unsigned u; bf16 h[2]; } t;
    t.h[0] = (bf16)a; t.h[1] = (bf16)b;
    return t.u;
}

// ---------------- flash attention: in-block split-KV x4 ----------------------
// One block per (bh, qtile-of-32). Wave w handles KV chunk [w*512,(w+1)*512),
// identical swapped-QK / in-register-softmax loop as round 5 (verified).
// Block-level flash merge in LDS: m* = max_w m_w; each wave scales its O,l by
// exp2(m_w - m*); O tree-summed (waves 2,3 -> 0,1; wave 1 -> 0); wave 0 writes.
// Round-6 lesson: (256,8) caps VGPR at 32 -> catastrophic spill (2.7 GB HBM
// scratch traffic/dispatch). Loop needs ~80 live VGPRs -> bound to 4 waves/EU.
__global__ __launch_bounds__(256, 4)
void attn(const bf16* __restrict__ q, const bf16* __restrict__ k,
          const bf16* __restrict__ vt, bf16* __restrict__ o) {
    __shared__ float mlds[4][32][2];                     // [wave][q][m,l]
    __shared__ __align__(16) float olds[2][32][64];      // [region][reg][lane] 16 KB
    int tid = threadIdx.x, lane = tid & 63, wid = tid >> 6;
    int ln = lane & 31, hi = lane >> 5, hi8 = hi * 8;
    int bh = blockIdx.x >> 6, qt = blockIdx.x & 63;
    int b = bh >> 3, h = bh & 7;
    int q0 = qt * 32;

    // Q fragments (B-operand): lane holds Q[q0+ln][c*16 + hi8 + 0..7]
    const bf16* qb = q + (((size_t)bh * NSEQ + q0 + ln) << 6) + hi8;
    bf16x8 qf0 = *reinterpret_cast<const bf16x8*>(qb);
    bf16x8 qf1 = *reinterpret_cast<const bf16x8*>(qb + 16);
    bf16x8 qf2 = *reinterpret_cast<const bf16x8*>(qb + 32);
    bf16x8 qf3 = *reinterpret_cast<const bf16x8*>(qb + 48);

    int kv_lo = wid << 9;                                // wave's 512-KV chunk
    const bf16* kr = k + (((size_t)b * NSEQ + kv_lo + ln) << 6) + hi8;
    const bf16* vr = vt + ((size_t)b * 64 + ln) * NSEQ + kv_lo + hi8;

    float m = -INFINITY, l = 0.f;
    f32x16 o0, o1;
    #pragma unroll
    for (int i = 0; i < 16; i++) { o0[i] = 0.f; o1[i] = 0.f; }

    for (int it = 0; it < 16; ++it) {
        // --- K fragments (A-operand)
        bf16x8 kf0 = *reinterpret_cast<const bf16x8*>(kr);
        bf16x8 kf1 = *reinterpret_cast<const bf16x8*>(kr + 16);
        bf16x8 kf2 = *reinterpret_cast<const bf16x8*>(kr + 32);
        bf16x8 kf3 = *reinterpret_cast<const bf16x8*>(kr + 48);
        kr += 32 * 64;

        // --- S^T (32 kv x 32 q), log2-scaled logits
        f32x16 s;
        #pragma unroll
        for (int i = 0; i < 16; i++) s[i] = 0.f;
        s = __builtin_amdgcn_mfma_f32_32x32x16_bf16(kf0, qf0, s, 0, 0, 0);
        s = __builtin_amdgcn_mfma_f32_32x32x16_bf16(kf1, qf1, s, 0, 0, 0);
        s = __builtin_amdgcn_mfma_f32_32x32x16_bf16(kf2, qf2, s, 0, 0, 0);
        s = __builtin_amdgcn_mfma_f32_32x32x16_bf16(kf3, qf3, s, 0, 0, 0);

        // --- V^T fragments for PV (issue loads early; overlap with softmax)
        bf16x8 v00 = *reinterpret_cast<const bf16x8*>(vr);
        bf16x8 v01 = *reinterpret_cast<const bf16x8*>(vr + 16);
        bf16x8 v10 = *reinterpret_cast<const bf16x8*>(vr + 32 * NSEQ);
        bf16x8 v11 = *reinterpret_cast<const bf16x8*>(vr + 32 * NSEQ + 16);
        vr += 32;

        // --- tile max over the 32 kv entries of this q (tree + cross-half shfl)
        float t8[8];
        #pragma unroll
        for (int i = 0; i < 8; i++) t8[i] = fmaxf(s[2 * i], s[2 * i + 1]);
        float t4a = fmaxf(t8[0], t8[1]), t4b = fmaxf(t8[2], t8[3]);
        float t4c = fmaxf(t8[4], t8[5]), t4d = fmaxf(t8[6], t8[7]);
        float tmax = fmaxf(fmaxf(t4a, t4b), fmaxf(t4c, t4d));
        tmax = fmaxf(tmax, __shfl_xor(tmax, 32));

        // --- defer-max rescale (T13, THR=8 in log2 domain)
        if (__any(tmax > m + 8.0f)) {
            float mn = fmaxf(m, tmax);
            float sc = __builtin_amdgcn_exp2f(m - mn);
            m = mn; l *= sc;
            #pragma unroll
            for (int i = 0; i < 16; i++) { o0[i] *= sc; o1[i] *= sc; }
        }

        // --- P = exp2(S - m), row-sum
        float p[16];
        #pragma unroll
        for (int i = 0; i < 16; i++) p[i] = __builtin_amdgcn_exp2f(s[i] - m);
        float u8[8];
        #pragma unroll
        for (int i = 0; i < 8; i++) u8[i] = p[2 * i] + p[2 * i + 1];
        float u4a = u8[0] + u8[1], u4b = u8[2] + u8[3];
        float u4c = u8[4] + u8[5], u4d = u8[6] + u8[7];
        float su = (u4a + u4b) + (u4c + u4d);
        su += __shfl_xor(su, 32);
        l += su;

        // --- P -> bf16 PV B-fragments (pack + shfl_xor(32) + select)
        unsigned A0 = packbf(p[0],  p[1]),  A1 = packbf(p[2],  p[3]);
        unsigned B0 = packbf(p[4],  p[5]),  B1 = packbf(p[6],  p[7]);
        unsigned C0 = packbf(p[8],  p[9]),  C1 = packbf(p[10], p[11]);
        unsigned D0 = packbf(p[12], p[13]), D1 = packbf(p[14], p[15]);
        unsigned A0x = __shfl_xor(A0, 32), A1x = __shfl_xor(A1, 32);
        unsigned B0x = __shfl_xor(B0, 32), B1x = __shfl_xor(B1, 32);
        unsigned C0x = __shfl_xor(C0, 32), C1x = __shfl_xor(C1, 32);
        unsigned D0x = __shfl_xor(D0, 32), D1x = __shfl_xor(D1, 32);
        union U { unsigned u[4]; bf16x8 v; } pf0, pf1;
        pf0.u[0] = hi ? B0x : A0;  pf0.u[1] = hi ? B1x : A1;
        pf0.u[2] = hi ? B0  : A0x; pf0.u[3] = hi ? B1  : A1x;
        pf1.u[0] = hi ? D0x : C0;  pf1.u[1] = hi ? D1x : C1;
        pf1.u[2] = hi ? D0  : C0x; pf1.u[3] = hi ? D1  : C1x;

        // --- O^T += V^T P   (two d-halves x two kv chunks)
        o0 = __builtin_amdgcn_mfma_f32_32x32x16_bf16(v00, pf0.v, o0, 0, 0, 0);
        o0 = __builtin_amdgcn_mfma_f32_32x32x16_bf16(v01, pf1.v, o0, 0, 0, 0);
        o1 = __builtin_amdgcn_mfma_f32_32x32x16_bf16(v10, pf0.v, o1, 0, 0, 0);
        o1 = __builtin_amdgcn_mfma_f32_32x32x16_bf16(v11, pf1.v, o1, 0, 0, 0);
    }

    // ---- block-level flash merge across the 4 KV-split waves ----
    if (!hi) { mlds[wid][ln][0] = m; mlds[wid][ln][1] = l; }
    __syncthreads();
    float m0 = mlds[0][ln][0], m1 = mlds[1][ln][0];
    float m2 = mlds[2][ln][0], m3 = mlds[3][ln][0];
    float mstar = fmaxf(fmaxf(m0, m1), fmaxf(m2, m3));
    float lstar = mlds[0][ln][1] * __builtin_amdgcn_exp2f(m0 - mstar)
                + mlds[1][ln][1] * __builtin_amdgcn_exp2f(m1 - mstar)
                + mlds[2][ln][1] * __builtin_amdgcn_exp2f(m2 - mstar)
                + mlds[3][ln][1] * __builtin_amdgcn_exp2f(m3 - mstar);
    float msc = __builtin_amdgcn_exp2f(m - mstar);
    #pragma unroll
    for (int i = 0; i < 16; i++) { o0[i] *= msc; o1[i] *= msc; }

    if (wid >= 2) {
        #pragma unroll
        for (int i = 0; i < 16; i++) {
            olds[wid - 2][i][lane]      = o0[i];
            olds[wid - 2][16 + i][lane] = o1[i];
        }
    }
    __syncthreads();
    if (wid < 2) {
        #pragma unroll
        for (int i = 0; i < 16; i++) {
            o0[i] += olds[wid][i][lane];
            o1[i] += olds[wid][16 + i][lane];
        }
    }
    __syncthreads();
    if (wid == 1) {
        #pragma unroll
        for (int i = 0; i < 16; i++) {
            olds[0][i][lane]      = o0[i];
            olds[0][16 + i][lane] = o1[i];
        }
    }
    __syncthreads();
    if (wid == 0) {
        #pragma unroll
        for (int i = 0; i < 16; i++) {
            o0[i] += olds[0][i][lane];
            o1[i] += olds[0][16 + i][lane];
        }
        float rl = 1.0f / lstar;
        bf16* ob = o + ((size_t)(b * NSEQ + q0 + ln)) * INNER + h * 64 + hi * 4;
        #pragma unroll
        for (int dh = 0; dh < 2; dh++) {
            const f32x16& oo = dh ? o1 : o0;
            #pragma unroll
            for (int g = 0; g < 4; g++) {
                bf16x4 pk;
                #pragma unroll
                for (int j = 0; j < 4; j++) pk[j] = (bf16)(oo[g * 4 + j] * rl);
                *reinterpret_cast<bf16x4*>(ob + dh * 32 + g * 8) = pk;
            }
        }
    }
}

// ---------------- launch -----------------------------------------------------
extern "C" void kernel_launch(void* const* d_in, const int* in_sizes, int n_in,
                              void* d_out, int out_size, void* d_ws, size_t ws_size,
                              hipStream_t stream) {
    const float* x   = (const float*)d_in[0];
    const float* Wq  = (const float*)d_in[1];
    const float* Wkv = (const float*)d_in[2];
    const float* Wo  = (const float*)d_in[3];
    const float* nw  = (const float*)d_in[4];
    const float* nb  = (const float*)d_in[5];
    const float* onw = (const float*)d_in[6];
    const float* onb = (const float*)d_in[7];
    float* out = (float*)d_out;
    char* ws = (char*)d_ws;

    bf16* xn   = (bf16*)(ws);                   // 16 MB  (8192x1024)
    bf16* qs   = (bf16*)(ws + (16u << 20));     //  8 MB  (4,8,2048,64)
    bf16* ks   = (bf16*)(ws + (24u << 20));     //  1 MB  (4,2048,64)
    bf16* vts  = (bf16*)(ws + (25u << 20));     //  1 MB  (4,64,2048)
    bf16* ao   = (bf16*)(ws + (26u << 20));     //  8 MB  (8192x512)
    bf16* wqkv = (bf16*)(ws + (34u << 20));     //  1.25 MB (640x1024)
    bf16* wo   = (bf16*)(ws + (36u << 20));     //  1 MB  (1024x512)

    prep_w<<<4608, 256, 0, stream>>>(Wq, Wkv, Wo, wqkv, wo);
    ln_bf16<<<8192, 256, 0, stream>>>(x, nw, nb, xn);
    gemm_bt<0><<<64 * 10, 256, 0, stream>>>(xn, wqkv, 1024, 10, qs, ks, vts, nullptr);
    attn<<<2048, 256, 0, stream>>>(qs, ks, vts, ao);
    gemm_bt<1><<<64 * 16, 256, 0, stream>>>(ao, wo, 512, 16, nullptr, nullptr, nullptr, out);
    ln_f32<<<8192, 256, 0, stream>>>(out, onw, onb);
}

// Round 8
// 214.918 us; speedup vs baseline: 3.5684x; 1.2875x over previous
//
#include <hip/hip_runtime.h>
#include <hip/hip_bf16.h>

typedef __bf16 bf16;
typedef __attribute__((ext_vector_type(4)))  float  f32x4;
typedef __attribute__((ext_vector_type(16))) float  f32x16;
typedef __attribute__((ext_vector_type(8)))  __bf16 bf16x8;
typedef __attribute__((ext_vector_type(4)))  __bf16 bf16x4;

#define NB    4
#define NSEQ  2048
#define DIM   1024
#define NH    8
#define DHEAD 64
#define INNER 512

// ---------------- weight prep: transpose + fp32->bf16 ------------------------
// Wq gets SCALE (64^-0.5) AND log2(e) folded in so attention softmax runs in
// exp2 domain with no per-element multiply.
__global__ __launch_bounds__(256) void prep_w(const float* __restrict__ Wq,
                                              const float* __restrict__ Wkv,
                                              const float* __restrict__ Wo,
                                              bf16* __restrict__ Wqkv_t,
                                              bf16* __restrict__ Wo_t) {
    int gid = blockIdx.x * 256 + threadIdx.x;
    const int N1 = 640 * 1024;            // Wqkv_t: 640 rows (n) x 1024 (k)
    if (gid < N1) {
        int n = gid >> 10, k = gid & 1023;
        float v;
        if (n < 512) v = Wq[k * 512 + n] * (0.125f * 1.44269504088896f);
        else         v = Wkv[k * 128 + (n - 512)];
        Wqkv_t[gid] = (bf16)v;
    } else {
        int g = gid - N1;                 // Wo_t: 1024 rows (n) x 512 (k)
        int n = g >> 9, k = g & 511;
        Wo_t[g] = (bf16)Wo[k * 1024 + n];
    }
}

// ---------------- layernorm fp32 -> bf16 ------------------------------------
__global__ __launch_bounds__(256) void ln_bf16(const float* __restrict__ x,
                                               const float* __restrict__ w,
                                               const float* __restrict__ b,
                                               bf16* __restrict__ out) {
    int row = blockIdx.x, tid = threadIdx.x;
    const float* xr = x + (size_t)row * DIM;
    f32x4 v = *reinterpret_cast<const f32x4*>(xr + tid * 4);
    float s1 = v[0] + v[1] + v[2] + v[3];
    float s2 = v[0]*v[0] + v[1]*v[1] + v[2]*v[2] + v[3]*v[3];
    #pragma unroll
    for (int off = 32; off; off >>= 1) { s1 += __shfl_xor(s1, off); s2 += __shfl_xor(s2, off); }
    __shared__ float red[8];
    int wid = tid >> 6, lane = tid & 63;
    if (!lane) { red[wid] = s1; red[4 + wid] = s2; }
    __syncthreads();
    s1 = red[0] + red[1] + red[2] + red[3];
    s2 = red[4] + red[5] + red[6] + red[7];
    float mu = s1 * (1.0f / DIM);
    float var = s2 * (1.0f / DIM) - mu * mu;
    float rs = rsqrtf(var + 1e-5f);
    f32x4 wv = *reinterpret_cast<const f32x4*>(w + tid * 4);
    f32x4 bv = *reinterpret_cast<const f32x4*>(b + tid * 4);
    bf16x4 o;
    #pragma unroll
    for (int i = 0; i < 4; i++) o[i] = (bf16)((v[i] - mu) * rs * wv[i] + bv[i]);
    *reinterpret_cast<bf16x4*>(out + (size_t)row * DIM + tid * 4) = o;
}

// ---------------- layernorm fp32 -> fp32 (in-place safe: row-local) ---------
__global__ __launch_bounds__(256) void ln_f32(float* __restrict__ io,
                                              const float* __restrict__ w,
                                              const float* __restrict__ b) {
    int row = blockIdx.x, tid = threadIdx.x;
    float* xr = io + (size_t)row * DIM;
    f32x4 v = *reinterpret_cast<const f32x4*>(xr + tid * 4);
    float s1 = v[0] + v[1] + v[2] + v[3];
    float s2 = v[0]*v[0] + v[1]*v[1] + v[2]*v[2] + v[3]*v[3];
    #pragma unroll
    for (int off = 32; off; off >>= 1) { s1 += __shfl_xor(s1, off); s2 += __shfl_xor(s2, off); }
    __shared__ float red[8];
    int wid = tid >> 6, lane = tid & 63;
    if (!lane) { red[wid] = s1; red[4 + wid] = s2; }
    __syncthreads();
    s1 = red[0] + red[1] + red[2] + red[3];
    s2 = red[4] + red[5] + red[6] + red[7];
    float mu = s1 * (1.0f / DIM);
    float var = s2 * (1.0f / DIM) - mu * mu;
    float rs = rsqrtf(var + 1e-5f);
    f32x4 wv = *reinterpret_cast<const f32x4*>(w + tid * 4);
    f32x4 bv = *reinterpret_cast<const f32x4*>(b + tid * 4);
    f32x4 o;
    #pragma unroll
    for (int i = 0; i < 4; i++) o[i] = (v[i] - mu) * rs * wv[i] + bv[i];
    *reinterpret_cast<f32x4*>(xr + tid * 4) = o;
}

// ---------------- GEMM  C = A(M x K) * Bt(N x K)^T,  bf16 MFMA 32x32x16 -----
// EPI 0 epilogue routes: q -> (b,h,n,d); K,V -> MFMA-fragment-native layouts
// (1-KB blocks; lane hi*32+ln owns a contiguous 16-B word) so the attn wave's
// loads are fully coalesced:
//   K elem (seq,d):   block ((b*64+seq/32)*4 + d/16),      word (d>>3&1)*32+seq%32, j=d&7
//   V^T elem (d,kv):  block ((b*64+kv/32)*4 + (d/32)*2 + (kv>>4&1)), word (kv>>3&1)*32+d%32, j=kv&7
template<int EPI>
__global__ __launch_bounds__(256)
void gemm_bt(const bf16* __restrict__ A, const bf16* __restrict__ Bt,
             int K, int ntiles,
             bf16* __restrict__ qo, bf16* __restrict__ ko, bf16* __restrict__ vo,
             float* __restrict__ fo) {
    __shared__ __align__(16) bf16 As[128 * 64];
    __shared__ __align__(16) bf16 Bs[64 * 64];
    int bid = blockIdx.x;
    int mt = bid / ntiles, nt = bid % ntiles;
    int m0 = mt * 128, n0 = nt * 64;
    int tid = threadIdx.x, lane = tid & 63, wid = tid >> 6;
    int wr = wid >> 1, wc = wid & 1;

    f32x16 acc[2];
    #pragma unroll
    for (int rt = 0; rt < 2; rt++)
        #pragma unroll
        for (int i = 0; i < 16; i++) acc[rt][i] = 0.f;

    char* AsB = reinterpret_cast<char*>(As);
    char* BsB = reinterpret_cast<char*>(Bs);

    for (int k0 = 0; k0 < K; k0 += 64) {
        #pragma unroll
        for (int i = 0; i < 4; i++) {           // A tile: 128 rows x 8 chunks(16B)
            int c = tid + 256 * i;
            int row = c >> 3, c16 = c & 7;
            f32x4 d = *reinterpret_cast<const f32x4*>(A + (size_t)(m0 + row) * K + k0 + c16 * 8);
            *reinterpret_cast<f32x4*>(AsB + row * 128 + ((c16 ^ (row & 7)) * 16)) = d;
        }
        #pragma unroll
        for (int i = 0; i < 2; i++) {           // B tile: 64 rows x 8 chunks
            int c = tid + 256 * i;
            int row = c >> 3, c16 = c & 7;
            f32x4 d = *reinterpret_cast<const f32x4*>(Bt + (size_t)(n0 + row) * K + k0 + c16 * 8);
            *reinterpret_cast<f32x4*>(BsB + row * 128 + ((c16 ^ (row & 7)) * 16)) = d;
        }
        __syncthreads();
        #pragma unroll
        for (int kc = 0; kc < 4; kc++) {
            int c16 = kc * 2 + (lane >> 5);
            int bn = wc * 32 + (lane & 31);
            bf16x8 bfr = *reinterpret_cast<bf16x8*>(BsB + bn * 128 + ((c16 ^ (bn & 7)) * 16));
            #pragma unroll
            for (int rt = 0; rt < 2; rt++) {
                int ar = wr * 64 + rt * 32 + (lane & 31);
                bf16x8 afr = *reinterpret_cast<bf16x8*>(AsB + ar * 128 + ((c16 ^ (ar & 7)) * 16));
                acc[rt] = __builtin_amdgcn_mfma_f32_32x32x16_bf16(afr, bfr, acc[rt], 0, 0, 0);
            }
        }
        __syncthreads();
    }

    int col = wc * 32 + (lane & 31);
    int gn = n0 + col;
    #pragma unroll
    for (int rt = 0; rt < 2; rt++) {
        int rbase = m0 + wr * 64 + rt * 32 + 4 * (lane >> 5);
        if (EPI == 0) {
            if (n0 < 512) {                     // q -> (b, h, n, d), scale pre-folded
                int h = gn >> 6, d = gn & 63;
                #pragma unroll
                for (int r = 0; r < 16; r++) {
                    int row = rbase + (r & 3) + 8 * (r >> 2);
                    int bb = row >> 11, seq = row & 2047;
                    qo[(((size_t)(bb * NH + h) * NSEQ + seq) << 6) + d] = (bf16)acc[rt][r];
                }
            } else if (n0 < 576) {              // k -> fragment-native (scalar stores)
                int d = gn - 512;
                int cd = d >> 4, hid = (d >> 3) & 1, jd = d & 7;
                #pragma unroll
                for (int r = 0; r < 16; r++) {
                    int row = rbase + (r & 3) + 8 * (r >> 2);
                    int bb = row >> 11, seq = row & 2047;
                    ko[(((size_t)((bb * 64 + (seq >> 5)) * 4 + cd)) << 9)
                       + (hid << 8) + ((seq & 31) << 3) + jd] = (bf16)acc[rt][r];
                }
            } else {                            // v -> fragment-native, packed x4
                int d = gn - 576;
                int ln2 = d & 31, cdh = (d >> 5) << 1;
                #pragma unroll
                for (int rq = 0; rq < 4; rq++) {
                    int row = rbase + 8 * rq;
                    int bb = row >> 11, kvq = row & 2047;
                    int c = cdh | ((kvq >> 4) & 1);
                    bf16x4 pk;
                    #pragma unroll
                    for (int j = 0; j < 4; j++) pk[j] = (bf16)acc[rt][rq * 4 + j];
                    *reinterpret_cast<bf16x4*>(vo + (((size_t)((bb * 64 + (kvq >> 5)) * 4 + c)) << 9)
                                                  + (((kvq >> 3) & 1) << 8) + (ln2 << 3) + (kvq & 7)) = pk;
                }
            }
        } else {                                // fp32 linear output, N=1024
            #pragma unroll
            for (int r = 0; r < 16; r++) {
                int row = rbase + (r & 3) + 8 * (r >> 2);
                fo[(size_t)row * 1024 + gn] = acc[rt][r];
            }
        }
    }
}

static __device__ __forceinline__ unsigned packbf(float a, float b) {
    union { unsigned u; bf16 h[2]; } t;
    t.h[0] = (bf16)a; t.h[1] = (bf16)b;
    return t.u;
}

// ---------------- flash attention: in-block split-KV x4 ----------------------
// One block per (bh, qtile-of-32). Wave w handles KV chunk [w*512,(w+1)*512).
// K/V now stored fragment-native: per 32-KV tile, K = 4 contiguous 1-KB blocks
// (kf0..kf3 at imm offsets 0/1/2/3 KB), V likewise (v00,v01,v10,v11). Each load
// is a fully-contiguous 1-KB wave read (8 cache lines, was 32).
// Round-6 lesson: (256,8) caps VGPR at 32 -> catastrophic spill. Bound = 4.
__global__ __launch_bounds__(256, 4)
void attn(const bf16* __restrict__ q, const bf16* __restrict__ k,
          const bf16* __restrict__ vt, bf16* __restrict__ o) {
    __shared__ float mlds[4][32][2];                     // [wave][q][m,l]
    __shared__ __align__(16) float olds[2][32][64];      // [region][reg][lane] 16 KB
    int tid = threadIdx.x, lane = tid & 63, wid = tid >> 6;
    int ln = lane & 31, hi = lane >> 5, hi8 = hi * 8;
    int bh = blockIdx.x >> 6, qt = blockIdx.x & 63;
    int b = bh >> 3, h = bh & 7;
    int q0 = qt * 32;

    // Q fragments (B-operand): lane holds Q[q0+ln][c*16 + hi8 + 0..7]
    const bf16* qb = q + (((size_t)bh * NSEQ + q0 + ln) << 6) + hi8;
    bf16x8 qf0 = *reinterpret_cast<const bf16x8*>(qb);
    bf16x8 qf1 = *reinterpret_cast<const bf16x8*>(qb + 16);
    bf16x8 qf2 = *reinterpret_cast<const bf16x8*>(qb + 32);
    bf16x8 qf3 = *reinterpret_cast<const bf16x8*>(qb + 48);

    // fragment-native K/V: tile t block base = (b*64 + t) * 2048 elements
    const bf16* kp = k  + (((size_t)(b * 64 + (wid << 4))) << 11) + (lane << 3);
    const bf16* vp = vt + (((size_t)(b * 64 + (wid << 4))) << 11) + (lane << 3);

    float m = -INFINITY, l = 0.f;
    f32x16 o0, o1;
    #pragma unroll
    for (int i = 0; i < 16; i++) { o0[i] = 0.f; o1[i] = 0.f; }

    for (int it = 0; it < 16; ++it) {
        // --- K fragments (A-operand), contiguous 1-KB wave loads
        bf16x8 kf0 = *reinterpret_cast<const bf16x8*>(kp);
        bf16x8 kf1 = *reinterpret_cast<const bf16x8*>(kp + 512);
        bf16x8 kf2 = *reinterpret_cast<const bf16x8*>(kp + 1024);
        bf16x8 kf3 = *reinterpret_cast<const bf16x8*>(kp + 1536);
        kp += 2048;

        // --- S^T (32 kv x 32 q), log2-scaled logits
        f32x16 s;
        #pragma unroll
        for (int i = 0; i < 16; i++) s[i] = 0.f;
        s = __builtin_amdgcn_mfma_f32_32x32x16_bf16(kf0, qf0, s, 0, 0, 0);
        s = __builtin_amdgcn_mfma_f32_32x32x16_bf16(kf1, qf1, s, 0, 0, 0);
        s = __builtin_amdgcn_mfma_f32_32x32x16_bf16(kf2, qf2, s, 0, 0, 0);
        s = __builtin_amdgcn_mfma_f32_32x32x16_bf16(kf3, qf3, s, 0, 0, 0);

        // --- V^T fragments for PV (issue loads early; overlap with softmax)
        bf16x8 v00 = *reinterpret_cast<const bf16x8*>(vp);
        bf16x8 v01 = *reinterpret_cast<const bf16x8*>(vp + 512);
        bf16x8 v10 = *reinterpret_cast<const bf16x8*>(vp + 1024);
        bf16x8 v11 = *reinterpret_cast<const bf16x8*>(vp + 1536);
        vp += 2048;

        // --- tile max over the 32 kv entries of this q (tree + cross-half shfl)
        float t8[8];
        #pragma unroll
        for (int i = 0; i < 8; i++) t8[i] = fmaxf(s[2 * i], s[2 * i + 1]);
        float t4a = fmaxf(t8[0], t8[1]), t4b = fmaxf(t8[2], t8[3]);
        float t4c = fmaxf(t8[4], t8[5]), t4d = fmaxf(t8[6], t8[7]);
        float tmax = fmaxf(fmaxf(t4a, t4b), fmaxf(t4c, t4d));
        tmax = fmaxf(tmax, __shfl_xor(tmax, 32));

        // --- defer-max rescale (T13, THR=8 in log2 domain)
        if (__any(tmax > m + 8.0f)) {
            float mn = fmaxf(m, tmax);
            float sc = __builtin_amdgcn_exp2f(m - mn);
            m = mn; l *= sc;
            #pragma unroll
            for (int i = 0; i < 16; i++) { o0[i] *= sc; o1[i] *= sc; }
        }

        // --- P = exp2(S - m), row-sum
        float p[16];
        #pragma unroll
        for (int i = 0; i < 16; i++) p[i] = __builtin_amdgcn_exp2f(s[i] - m);
        float u8[8];
        #pragma unroll
        for (int i = 0; i < 8; i++) u8[i] = p[2 * i] + p[2 * i + 1];
        float u4a = u8[0] + u8[1], u4b = u8[2] + u8[3];
        float u4c = u8[4] + u8[5], u4d = u8[6] + u8[7];
        float su = (u4a + u4b) + (u4c + u4d);
        su += __shfl_xor(su, 32);
        l += su;

        // --- P -> bf16 PV B-fragments (pack + shfl_xor(32) + select)
        unsigned A0 = packbf(p[0],  p[1]),  A1 = packbf(p[2],  p[3]);
        unsigned B0 = packbf(p[4],  p[5]),  B1 = packbf(p[6],  p[7]);
        unsigned C0 = packbf(p[8],  p[9]),  C1 = packbf(p[10], p[11]);
        unsigned D0 = packbf(p[12], p[13]), D1 = packbf(p[14], p[15]);
        unsigned A0x = __shfl_xor(A0, 32), A1x = __shfl_xor(A1, 32);
        unsigned B0x = __shfl_xor(B0, 32), B1x = __shfl_xor(B1, 32);
        unsigned C0x = __shfl_xor(C0, 32), C1x = __shfl_xor(C1, 32);
        unsigned D0x = __shfl_xor(D0, 32), D1x = __shfl_xor(D1, 32);
        union U { unsigned u[4]; bf16x8 v; } pf0, pf1;
        pf0.u[0] = hi ? B0x : A0;  pf0.u[1] = hi ? B1x : A1;
        pf0.u[2] = hi ? B0  : A0x; pf0.u[3] = hi ? B1  : A1x;
        pf1.u[0] = hi ? D0x : C0;  pf1.u[1] = hi ? D1x : C1;
        pf1.u[2] = hi ? D0  : C0x; pf1.u[3] = hi ? D1  : C1x;

        // --- O^T += V^T P   (two d-halves x two kv chunks)
        o0 = __builtin_amdgcn_mfma_f32_32x32x16_bf16(v00, pf0.v, o0, 0, 0, 0);
        o0 = __builtin_amdgcn_mfma_f32_32x32x16_bf16(v01, pf1.v, o0, 0, 0, 0);
        o1 = __builtin_amdgcn_mfma_f32_32x32x16_bf16(v10, pf0.v, o1, 0, 0, 0);
        o1 = __builtin_amdgcn_mfma_f32_32x32x16_bf16(v11, pf1.v, o1, 0, 0, 0);
    }

    // ---- block-level flash merge across the 4 KV-split waves ----
    if (!hi) { mlds[wid][ln][0] = m; mlds[wid][ln][1] = l; }
    __syncthreads();
    float m0 = mlds[0][ln][0], m1 = mlds[1][ln][0];
    float m2 = mlds[2][ln][0], m3 = mlds[3][ln][0];
    float mstar = fmaxf(fmaxf(m0, m1), fmaxf(m2, m3));
    float lstar = mlds[0][ln][1] * __builtin_amdgcn_exp2f(m0 - mstar)
                + mlds[1][ln][1] * __builtin_amdgcn_exp2f(m1 - mstar)
                + mlds[2][ln][1] * __builtin_amdgcn_exp2f(m2 - mstar)
                + mlds[3][ln][1] * __builtin_amdgcn_exp2f(m3 - mstar);
    float msc = __builtin_amdgcn_exp2f(m - mstar);
    #pragma unroll
    for (int i = 0; i < 16; i++) { o0[i] *= msc; o1[i] *= msc; }

    if (wid >= 2) {
        #pragma unroll
        for (int i = 0; i < 16; i++) {
            olds[wid - 2][i][lane]      = o0[i];
            olds[wid - 2][16 + i][lane] = o1[i];
        }
    }
    __syncthreads();
    if (wid < 2) {
        #pragma unroll
        for (int i = 0; i < 16; i++) {
            o0[i] += olds[wid][i][lane];
            o1[i] += olds[wid][16 + i][lane];
        }
    }
    __syncthreads();
    if (wid == 1) {
        #pragma unroll
        for (int i = 0; i < 16; i++) {
            olds[0][i][lane]      = o0[i];
            olds[0][16 + i][lane] = o1[i];
        }
    }
    __syncthreads();
    if (wid == 0) {
        #pragma unroll
        for (int i = 0; i < 16; i++) {
            o0[i] += olds[0][i][lane];
            o1[i] += olds[0][16 + i][lane];
        }
        float rl = 1.0f / lstar;
        bf16* ob = o + ((size_t)(b * NSEQ + q0 + ln)) * INNER + h * 64 + hi * 4;
        #pragma unroll
        for (int dh = 0; dh < 2; dh++) {
            const f32x16& oo = dh ? o1 : o0;
            #pragma unroll
            for (int g = 0; g < 4; g++) {
                bf16x4 pk;
                #pragma unroll
                for (int j = 0; j < 4; j++) pk[j] = (bf16)(oo[g * 4 + j] * rl);
                *reinterpret_cast<bf16x4*>(ob + dh * 32 + g * 8) = pk;
            }
        }
    }
}

// ---------------- launch -----------------------------------------------------
extern "C" void kernel_launch(void* const* d_in, const int* in_sizes, int n_in,
                              void* d_out, int out_size, void* d_ws, size_t ws_size,
                              hipStream_t stream) {
    const float* x   = (const float*)d_in[0];
    const float* Wq  = (const float*)d_in[1];
    const float* Wkv = (const float*)d_in[2];
    const float* Wo  = (const float*)d_in[3];
    const float* nw  = (const float*)d_in[4];
    const float* nb  = (const float*)d_in[5];
    const float* onw = (const float*)d_in[6];
    const float* onb = (const float*)d_in[7];
    float* out = (float*)d_out;
    char* ws = (char*)d_ws;

    bf16* xn   = (bf16*)(ws);                   // 16 MB  (8192x1024)
    bf16* qs   = (bf16*)(ws + (16u << 20));     //  8 MB  (4,8,2048,64)
    bf16* ks   = (bf16*)(ws + (24u << 20));     //  1 MB  K fragment-native
    bf16* vts  = (bf16*)(ws + (25u << 20));     //  1 MB  V fragment-native
    bf16* ao   = (bf16*)(ws + (26u << 20));     //  8 MB  (8192x512)
    bf16* wqkv = (bf16*)(ws + (34u << 20));     //  1.25 MB (640x1024)
    bf16* wo   = (bf16*)(ws + (36u << 20));     //  1 MB  (1024x512)

    prep_w<<<4608, 256, 0, stream>>>(Wq, Wkv, Wo, wqkv, wo);
    ln_bf16<<<8192, 256, 0, stream>>>(x, nw, nb, xn);
    gemm_bt<0><<<64 * 10, 256, 0, stream>>>(xn, wqkv, 1024, 10, qs, ks, vts, nullptr);
    attn<<<2048, 256, 0, stream>>>(qs, ks, vts, ao);
    gemm_bt<1><<<64 * 16, 256, 0, stream>>>(ao, wo, 512, 16, nullptr, nullptr, nullptr, out);
    ln_f32<<<8192, 256, 0, stream>>>(out, onw, onb);
}